// Round 4
// baseline (223.458 us; speedup 1.0000x reference)
//
#include <hip/hip_runtime.h>
#include <math.h>

#define B 32
#define H 8
#define C 64
#define L 1024
#define HC (H * C)            // 512
#define K 6

#define SLICES 16
#define SLICE_L (L / SLICES)           // 64 l's per block
#define GROUPS 16                      // 16-lane groups per 256-thread block
#define ROWS_PER_GROUP (HC / GROUPS)   // 32 rows each
#define TOTAL_BLOCKS (B * SLICES)      // 512 -> 2 blocks/CU

// ---------------------------------------------------------------------------
// Stage 1 (fused): mean_value[b][l] = mean over 512 (h,c) rows of corr,
// then the LAST block to finish (device-scope counter) computes the column
// mean over b, top-6 (tie-break smaller index, matching lax.top_k) and the
// per-batch softmax — removing a separate single-block launch from the
// serial chain. No spin-waits; counter only selects the finalizer block.
// ---------------------------------------------------------------------------
__global__ __launch_bounds__(256) void mean_topk_kernel(
    const float* __restrict__ corr,
    float* __restrict__ mean_value,     // [B][L]
    float* __restrict__ tmp_corr,       // [B][K]
    int* __restrict__ index_out,        // [K]
    unsigned int* __restrict__ counter) {
    __shared__ float sacc[GROUPS * SLICE_L];   // 4 KB
    __shared__ unsigned int s_old;
    int blk = blockIdx.x;                      // 0..511
    int b = blk / SLICES;
    int s = blk % SLICES;
    int t = threadIdx.x;
    int g = t >> 4;                            // group 0..15
    int j = t & 15;                            // lane-in-group

    // ---- phase 1: this block's mean slice -------------------------------
    const float4* base =
        (const float4*)(corr + (size_t)b * HC * L + s * SLICE_L);
    float4 acc = make_float4(0.f, 0.f, 0.f, 0.f);
    #pragma unroll 8
    for (int i = 0; i < ROWS_PER_GROUP; ++i) {
        int r = g + GROUPS * i;                // rows g, g+16, ...
        float4 v = base[(size_t)r * (L / 4) + j];
        acc.x += v.x; acc.y += v.y; acc.z += v.z; acc.w += v.w;
    }
    ((float4*)sacc)[g * (SLICE_L / 4) + j] = acc;
    __syncthreads();

    if (t < SLICE_L) {
        float m = 0.f;
        #pragma unroll
        for (int g2 = 0; g2 < GROUPS; ++g2) m += sacc[g2 * SLICE_L + t];
        mean_value[b * L + s * SLICE_L + t] = m * (1.0f / HC);
    }

    // ---- completion counter (release) -----------------------------------
    __threadfence();
    if (t == 0) s_old = atomicAdd(counter, 1u);
    __syncthreads();
    if (s_old != TOTAL_BLOCKS - 1) return;     // block-uniform exit
    __threadfence();                           // acquire side

    // ---- phase 2 (last block only): colmean + top-6 + softmax -----------
    float cm[4];
    #pragma unroll
    for (int q = 0; q < 4; ++q) {
        int l = t + 256 * q;
        float sum = 0.f;
        #pragma unroll
        for (int bb = 0; bb < B; ++bb) sum += mean_value[bb * L + l];
        cm[q] = sum * (1.0f / B);
    }

    __shared__ float wv[4];
    __shared__ int   wi[4];
    __shared__ int   sel[K];
    int lane = t & 63;
    int wave = t >> 6;

    for (int k = 0; k < K; ++k) {
        // local argmax over this thread's 4 l's (ascending l -> ties keep smaller)
        float v = -3.0e38f; int i = 0x7fffffff;
        #pragma unroll
        for (int q = 0; q < 4; ++q)
            if (cm[q] > v) { v = cm[q]; i = t + 256 * q; }
        // wave argmax, tie-break smaller index
        #pragma unroll
        for (int off = 32; off >= 1; off >>= 1) {
            float v2 = __shfl_xor(v, off, 64);
            int   i2 = __shfl_xor(i, off, 64);
            if (v2 > v || (v2 == v && i2 < i)) { v = v2; i = i2; }
        }
        if (lane == 0) { wv[wave] = v; wi[wave] = i; }
        __syncthreads();
        if (wave == 0) {
            float v3 = (lane < 4) ? wv[lane] : -3.0e38f;
            int   i3 = (lane < 4) ? wi[lane] : 0x7fffffff;
            #pragma unroll
            for (int off = 2; off >= 1; off >>= 1) {
                float v2 = __shfl_xor(v3, off, 64);
                int   i2 = __shfl_xor(i3, off, 64);
                if (v2 > v3 || (v2 == v3 && i2 < i3)) { v3 = v2; i3 = i2; }
            }
            if (lane == 0) sel[k] = i3;
        }
        __syncthreads();
        #pragma unroll
        for (int q = 0; q < 4; ++q)
            if (t + 256 * q == sel[k]) cm[q] = -3.0e38f;
    }

    if (t < K) index_out[t] = sel[t];
    if (t < B) {
        float w[K];
        float m = -3.0e38f;
        #pragma unroll
        for (int k = 0; k < K; ++k) {
            w[k] = mean_value[t * L + sel[k]];
            m = fmaxf(m, w[k]);
        }
        float sum = 0.f;
        #pragma unroll
        for (int k = 0; k < K; ++k) { w[k] = expf(w[k] - m); sum += w[k]; }
        float inv = 1.0f / sum;
        #pragma unroll
        for (int k = 0; k < K; ++k) tmp_corr[t * K + k] = w[k] * inv;
    }
}

// ---------------------------------------------------------------------------
// Stage 2: out[b,h,c,l] = sum_k w[b,k] * values[b,h,c,(l+idx[k]) % L]
// One block per (b,h,c) row; row staged in LDS (4 KB) with float4.
// Each thread owns l = tid, tid+256, tid+512, tid+768: LDS reads are
// lane-consecutive (2 lanes/bank = conflict-free); stores are coalesced
// dword stores. HBM-bound; LDS cost ~560 cyc/block << HBM time.
// ---------------------------------------------------------------------------
__global__ __launch_bounds__(256) void agg_kernel(
    const float* __restrict__ values,
    const float* __restrict__ tmp_corr,
    const int* __restrict__ index,
    float* __restrict__ out) {
    __shared__ float row[L];
    __shared__ float ws[K];
    __shared__ int   is[K];
    int blk = blockIdx.x;                  // 0 .. B*H*C-1
    int b = blk / HC;
    int tid = threadIdx.x;

    ((float4*)row)[tid] = ((const float4*)(values + (size_t)blk * L))[tid];
    if (tid < K) { ws[tid] = tmp_corr[b * K + tid]; is[tid] = index[tid]; }
    __syncthreads();

    float w[K]; int d[K];
    #pragma unroll
    for (int k = 0; k < K; ++k) { w[k] = ws[k]; d[k] = is[k]; }

    float* orow = out + (size_t)blk * L;
    #pragma unroll
    for (int off = 0; off < L; off += 256) {
        int l = tid + off;
        float acc = 0.f;
        #pragma unroll
        for (int k = 0; k < K; ++k)
            acc += w[k] * row[(l + d[k]) & (L - 1)];
        orow[l] = acc;
    }
}

// ---------------------------------------------------------------------------
extern "C" void kernel_launch(void* const* d_in, const int* in_sizes, int n_in,
                              void* d_out, int out_size, void* d_ws, size_t ws_size,
                              hipStream_t stream) {
    const float* values = (const float*)d_in[0];
    const float* corr   = (const float*)d_in[1];
    float* out = (float*)d_out;

    // workspace layout
    float* mean_value = (float*)d_ws;                       // B*L floats
    float* tmp_corr   = mean_value + (size_t)B * L;         // B*K floats
    int*   index      = (int*)(tmp_corr + B * K);           // K ints
    unsigned int* counter = (unsigned int*)(index + K + 2); // 4-byte aligned

    hipMemsetAsync(counter, 0, sizeof(unsigned int), stream);
    mean_topk_kernel<<<TOTAL_BLOCKS, 256, 0, stream>>>(
        corr, mean_value, tmp_corr, index, counter);
    agg_kernel<<<B * H * C, 256, 0, stream>>>(values, tmp_corr, index, out);
}